// Round 8
// baseline (202.681 us; speedup 1.0000x reference)
//
#include <hip/hip_runtime.h>
#include <hip/hip_bf16.h>

// 2-NN: out[q] = sum of 2 smallest ||q - t||^2 over 200000 train points.
// d2 = q_sq + t_sq - 2*q.t ; top-2 depends only on s = t_sq - 2*q.t.
// v8: 1-WAVE WORKGROUPS, ZERO BARRIERS. r2/r4/r7 all pinned at MfmaUtil ~34%
//     (barrier-lockstep serialization); r5 proved chunks are L2-resident via
//     the XCD remap. Here each 64-thread block stages its own 16-pt tile with
//     global_load_lds (producer == consumer == one wave -> wave-synchronous),
//     double-buffered, readiness via counted s_waitcnt vmcnt(5) (never 0 in
//     steady state). 8 KB LDS/block -> ~16 independent waves/CU for TLP.
//     Queries pre-scaled by -2; t_sq injected via MFMA C-in.

typedef short bf16x8 __attribute__((ext_vector_type(8)));   // 8 bf16 = 4 VGPRs
typedef float f32x4 __attribute__((ext_vector_type(4)));

#define N_TRAIN 200000
#define M_QUERY 2048
#define DIMS 128

__device__ __forceinline__ unsigned int bf_bits(float f) {
  unsigned int u = __float_as_uint(f);
  return (u + 0x7FFFu + ((u >> 16) & 1u)) >> 16;
}

// 8 lanes per row; each lane handles 16 contiguous floats (64B) -> coalesced.
// dst holds bf16(scale * src); sq holds exact fp32 ||row||^2 of UNSCALED src.
__global__ __launch_bounds__(256) void convert_kernel(
    const float* __restrict__ src, unsigned short* __restrict__ dst,
    float* __restrict__ sq, int nrows, float scale) {
  int gtid = blockIdx.x * 256 + threadIdx.x;
  int row = gtid >> 3, sub = gtid & 7;
  if (row >= nrows) return;
  const float4* s4 = reinterpret_cast<const float4*>(src + (size_t)row * DIMS + sub * 16);
  unsigned int pk[8];
  float acc = 0.f;
#pragma unroll
  for (int i = 0; i < 4; ++i) {
    float4 v = s4[i];
    acc += v.x * v.x + v.y * v.y + v.z * v.z + v.w * v.w;
    pk[i * 2 + 0] = bf_bits(v.x * scale) | (bf_bits(v.y * scale) << 16);
    pk[i * 2 + 1] = bf_bits(v.z * scale) | (bf_bits(v.w * scale) << 16);
  }
  uint4* d4 = reinterpret_cast<uint4*>(dst + (size_t)row * DIMS + sub * 16);
  d4[0] = make_uint4(pk[0], pk[1], pk[2], pk[3]);
  d4[1] = make_uint4(pk[4], pk[5], pk[6], pk[7]);
  acc += __shfl_xor(acc, 1);
  acc += __shfl_xor(acc, 2);
  acc += __shfl_xor(acc, 4);
  if (sub == 0) sq[row] = acc;
}

// Main. ONE wave per block, owns 64 queries (4 m-tiles of 16), streams its
// chunk 16 points at a time through its private double-buffered LDS tile.
// Block remap: xcd = b&7 (HW round-robin); a chunk's 32 qgroups share an XCD.
template <int NCH>
__global__ __launch_bounds__(64) void knn_main(
    const unsigned short* __restrict__ tb, const unsigned short* __restrict__ qb16,
    const float* __restrict__ tsq, float* __restrict__ partials) {
  constexpr int PPC = N_TRAIN / NCH;        // 1600
  constexpr int ITERS = PPC / 16;           // 100 (even)
  const int b = blockIdx.x;                 // grid = NCH*32
  const int g = (b & 7) * (NCH * 4) + (b >> 3);
  const int chunk = g >> 5;
  const int qw = (g & 31) << 6;
  const int l = threadIdx.x;                // 0..63
  const int lo = l & 15, hi = l >> 4;

  __shared__ char smem[2 * 4096];           // 2 x 16-point tiles

  // A-fragments (hold -2*q in bf16): Q[qw + t*16 + lo][kf*32 + hi*8 .. +8]
  bf16x8 a[4][4];
#pragma unroll
  for (int t = 0; t < 4; ++t)
#pragma unroll
    for (int kf = 0; kf < 4; ++kf)
      a[t][kf] = *reinterpret_cast<const bf16x8*>(
          qb16 + (size_t)(qw + t * 16 + lo) * DIMS + kf * 32 + hi * 8);

  // gll staging of a 16-row x 256B tile, LDS linear, source pre-swizzled so
  // LDS[row][blk] = G[row][blk ^ (row&7)]. gll quarter k covers rows 4k..4k+3:
  // lane offset (row = 4k + hi): k even -> row&7 = hi ; k odd -> row&7 = 4+hi.
  const int offE = hi * 256 + ((lo ^ hi) << 4);              // k=0 (+2048: k=2)
  const int offO = (4 + hi) * 256 + ((lo ^ (4 + hi)) << 4);  // k=1 (+2048: k=3)
  const char* gt = reinterpret_cast<const char*>(tb) + (size_t)chunk * PPC * 256;
  const float* tq = tsq + chunk * PPC;

  // ds_read: B-frag for point p=lo, blk kb = kf*4+hi: addr = p*256+((kb^(p&7))<<4)
  int roff[4];
#pragma unroll
  for (int kf = 0; kf < 4; ++kf)
    roff[kf] = lo * 256 + ((((kf << 2) + hi) ^ (lo & 7)) << 4);

  const float INF = __builtin_inff();
  float best1[4][4], best2[4][4];
#pragma unroll
  for (int t = 0; t < 4; ++t)
#pragma unroll
    for (int r = 0; r < 4; ++r) { best1[t][r] = INF; best2[t][r] = INF; }

  // ISSUE: 4 gll (1 KB each) + 1 t_sq load = 5 vmem ops per tile-group.
#define ISSUE(T, P, TV)                                                        \
  do {                                                                         \
    const char* _s = gt + (size_t)(T) * 4096;                                  \
    char* _d = smem + (P) * 4096;                                              \
    __builtin_amdgcn_global_load_lds(                                          \
        (const __attribute__((address_space(1))) void*)(_s + offE),            \
        (__attribute__((address_space(3))) void*)_d, 16, 0, 0);                \
    __builtin_amdgcn_global_load_lds(                                          \
        (const __attribute__((address_space(1))) void*)(_s + offO),            \
        (__attribute__((address_space(3))) void*)(_d + 1024), 16, 0, 0);       \
    __builtin_amdgcn_global_load_lds(                                          \
        (const __attribute__((address_space(1))) void*)(_s + 2048 + offE),     \
        (__attribute__((address_space(3))) void*)(_d + 2048), 16, 0, 0);       \
    __builtin_amdgcn_global_load_lds(                                          \
        (const __attribute__((address_space(1))) void*)(_s + 2048 + offO),     \
        (__attribute__((address_space(3))) void*)(_d + 3072), 16, 0, 0);       \
    TV = tq[(T) * 16 + lo];                                                    \
  } while (0)

#define COMPUTE(P, TV)                                                         \
  do {                                                                         \
    const char* _buf = smem + (P) * 4096;                                      \
    bf16x8 f[4];                                                               \
    _Pragma("unroll")                                                          \
    for (int kf = 0; kf < 4; ++kf)                                             \
      f[kf] = *reinterpret_cast<const bf16x8*>(_buf + roff[kf]);               \
    f32x4 c = {TV, TV, TV, TV};                                                \
    _Pragma("unroll")                                                          \
    for (int t = 0; t < 4; ++t) {                                              \
      f32x4 acc = __builtin_amdgcn_mfma_f32_16x16x32_bf16(a[t][0], f[0], c, 0, 0, 0); \
      acc = __builtin_amdgcn_mfma_f32_16x16x32_bf16(a[t][1], f[1], acc, 0, 0, 0);     \
      acc = __builtin_amdgcn_mfma_f32_16x16x32_bf16(a[t][2], f[2], acc, 0, 0, 0);     \
      acc = __builtin_amdgcn_mfma_f32_16x16x32_bf16(a[t][3], f[3], acc, 0, 0, 0);     \
      _Pragma("unroll")                                                        \
      for (int r = 0; r < 4; ++r) {                                            \
        float s0 = acc[r]; /* = t_sq - 2 q.t (C-in carried t_sq) */            \
        float n1 = fminf(best1[t][r], s0);                                     \
        float n2 = __builtin_amdgcn_fmed3f(best1[t][r], best2[t][r], s0);      \
        best1[t][r] = n1;                                                      \
        best2[t][r] = n2;                                                      \
      }                                                                        \
    }                                                                          \
  } while (0)

  float tvA, tvB;
  ISSUE(0, 0, tvA);
  ISSUE(1, 1, tvB);

  for (int it = 0; it + 2 < ITERS; it += 2) {
    asm volatile("s_waitcnt vmcnt(5)" ::: "memory");  // tile it + tvA landed
    COMPUTE(0, tvA);
    ISSUE(it + 2, 0, tvA);                            // buf0 reads already retired
    asm volatile("s_waitcnt vmcnt(5)" ::: "memory");  // tile it+1 + tvB landed
    COMPUTE(1, tvB);
    ISSUE(it + 3, 1, tvB);
  }
  asm volatile("s_waitcnt vmcnt(5)" ::: "memory");
  COMPUTE(0, tvA);                                    // tile ITERS-2 (even -> buf0)
  asm volatile("s_waitcnt vmcnt(0)" ::: "memory");
  COMPUTE(1, tvB);                                    // tile ITERS-1

#undef ISSUE
#undef COMPUTE

  // merge top-2 across the 16 lanes (columns) sharing each query
#pragma unroll
  for (int t = 0; t < 4; ++t)
#pragma unroll
    for (int r = 0; r < 4; ++r) {
      float v1 = best1[t][r], v2 = best2[t][r];
#pragma unroll
      for (int m = 1; m < 16; m <<= 1) {
        float o1 = __shfl_xor(v1, m);
        float o2 = __shfl_xor(v2, m);
        float n1 = fminf(v1, o1);
        float n2 = fminf(fmaxf(v1, o1), fminf(v2, o2));
        v1 = n1;
        v2 = n2;
      }
      best1[t][r] = v1;
      best2[t][r] = v2;
    }
  if (lo == 0) {
#pragma unroll
    for (int t = 0; t < 4; ++t)
#pragma unroll
      for (int r = 0; r < 4; ++r) {
        int q = qw + t * 16 + hi * 4 + r;
        float* p = partials + ((size_t)chunk * M_QUERY + q) * 2;
        p[0] = best1[t][r];
        p[1] = best2[t][r];
      }
  }
}

__global__ __launch_bounds__(256) void knn_reduce(
    const float* __restrict__ partials, const float* __restrict__ qsq,
    float* __restrict__ out, int nchunk) {
  int q = blockIdx.x * 256 + threadIdx.x;
  if (q >= M_QUERY) return;
  const float INF = __builtin_inff();
  float b1 = INF, b2 = INF;
  for (int c = 0; c < nchunk; ++c) {
    const float* p = partials + ((size_t)c * M_QUERY + q) * 2;
    float v = p[0];
    float n1 = fminf(b1, v);
    float n2 = __builtin_amdgcn_fmed3f(b1, b2, v);
    b1 = n1; b2 = n2;
    v = p[1];
    n1 = fminf(b1, v);
    n2 = __builtin_amdgcn_fmed3f(b1, b2, v);
    b1 = n1; b2 = n2;
  }
  out[q] = 2.f * qsq[q] + b1 + b2;
}

extern "C" void kernel_launch(void* const* d_in, const int* in_sizes, int n_in,
                              void* d_out, int out_size, void* d_ws, size_t ws_size,
                              hipStream_t stream) {
  const float* train = (const float*)d_in[0];  // 200000 x 128 f32
  const float* test  = (const float*)d_in[1];  // 2048 x 128 f32
  float* out = (float*)d_out;                  // 2048 f32
  char* ws = (char*)d_ws;

  size_t off_tb  = 0;                                      // train bf16: 51,200,000 B
  size_t off_qb  = off_tb  + (size_t)N_TRAIN * DIMS * 2;   // query bf16 (-2q)
  size_t off_tsq = off_qb  + (size_t)M_QUERY * DIMS * 2;   // t_sq
  size_t off_qsq = off_tsq + (size_t)N_TRAIN * 4;          // q_sq
  size_t off_pt  = off_qsq + (size_t)M_QUERY * 4;          // partials
  size_t need125 = off_pt + (size_t)125 * M_QUERY * 2 * 4;
  if (ws_size < need125) return;

  unsigned short* tbp = (unsigned short*)(ws + off_tb);
  unsigned short* qb  = (unsigned short*)(ws + off_qb);
  float* tsq = (float*)(ws + off_tsq);
  float* qsq = (float*)(ws + off_qsq);
  float* part = (float*)(ws + off_pt);

  hipLaunchKernelGGL(convert_kernel, dim3((N_TRAIN * 8) / 256), dim3(256), 0, stream,
                     train, tbp, tsq, N_TRAIN, 1.0f);
  hipLaunchKernelGGL(convert_kernel, dim3((M_QUERY * 8) / 256), dim3(256), 0, stream,
                     test, qb, qsq, M_QUERY, -2.0f);
  hipLaunchKernelGGL(knn_main<125>, dim3(125 * 32), dim3(64), 0, stream,
                     tbp, qb, tsq, part);
  hipLaunchKernelGGL(knn_reduce, dim3(M_QUERY / 256), dim3(256), 0, stream,
                     part, qsq, out, 125);
}